// Round 2
// baseline (429.729 us; speedup 1.0000x reference)
//
#include <hip/hip_runtime.h>

// GCN 3-layer fused pipeline for MI355X.
// N=50000 nodes, E=800000 edges, F=128 features.
// edge_index is staged by the harness as int32 (harness converts integer inputs
// to int32) with layout [row[0..E), col[0..E)].
// Strategy: build dest-sorted CSR once per call, then per layer:
//   g = dinv * (X' @ W)   (X' = relu(dinv*agg_prev + b_prev) fused into load)
//   agg[v] = g[v] + sum_{in-edges} g[src]   (gather, no atomics)

__global__ __launch_bounds__(256) void k_prep(const int* __restrict__ ei,
                                              int* __restrict__ cnt, int E, int N) {
  int e = blockIdx.x * 256 + threadIdx.x;
  if (e < E) {
    unsigned c = (unsigned)ei[E + e];
    if (c < (unsigned)N) atomicAdd(&cnt[c], 1);
  }
}

__global__ __launch_bounds__(256) void k_dinv(const int* __restrict__ cnt, float* __restrict__ dinv, int N) {
  int v = blockIdx.x * 256 + threadIdx.x;
  if (v < N) dinv[v] = rsqrtf((float)(cnt[v] + 1));  // +1 self loop; always > 0
}

__global__ __launch_bounds__(256) void k_scan1(const int* __restrict__ cnt, int* __restrict__ offs,
                                               int* __restrict__ bsum, int N) {
  __shared__ int s[256];
  int tid = threadIdx.x;
  int i = blockIdx.x * 256 + tid;
  int v = (i < N) ? cnt[i] : 0;
  s[tid] = v;
  __syncthreads();
  for (int d = 1; d < 256; d <<= 1) {
    int t = (tid >= d) ? s[tid - d] : 0;
    __syncthreads();
    s[tid] += t;
    __syncthreads();
  }
  if (i < N) offs[i] = s[tid] - v;  // block-local exclusive
  if (tid == 255) bsum[blockIdx.x] = s[255];
}

__global__ __launch_bounds__(256) void k_scan2(int* __restrict__ bsum, int B) {
  __shared__ int s[256];
  int tid = threadIdx.x;
  int v = (tid < B) ? bsum[tid] : 0;
  s[tid] = v;
  __syncthreads();
  for (int d = 1; d < 256; d <<= 1) {
    int t = (tid >= d) ? s[tid - d] : 0;
    __syncthreads();
    s[tid] += t;
    __syncthreads();
  }
  if (tid < B) bsum[tid] = s[tid] - v;  // exclusive block offsets
}

__global__ __launch_bounds__(256) void k_scan3(int* __restrict__ offs, const int* __restrict__ bsum,
                                               int* __restrict__ cursor, int N, int E) {
  int i = blockIdx.x * 256 + threadIdx.x;
  if (i < N) {
    int o = offs[i] + bsum[blockIdx.x];
    offs[i] = o;
    cursor[i] = o;
  }
  if (i == 0) offs[N] = E;
}

__global__ __launch_bounds__(256) void k_fill(const int* __restrict__ ei,
                                              int* __restrict__ cursor, int* __restrict__ csr_src,
                                              int E, int N) {
  int e = blockIdx.x * 256 + threadIdx.x;
  if (e < E) {
    unsigned r = (unsigned)ei[e];
    unsigned c = (unsigned)ei[E + e];
    if (c < (unsigned)N && r < (unsigned)N) {
      int p = atomicAdd(&cursor[c], 1);
      csr_src[p] = (int)r;
    }
  }
}

// GEMM: G[row][col] = dinv[row] * sum_k X'[row][k] * W[k][col]
// MODE 0: X' = X (raw).  MODE 1: X'[r][k] = relu(dinv[r]*X[r][k] + bias[k]).
// Block: 256 threads -> 32 rows x 128 cols tile; thread = 4 rows x 4 cols.
template <int MODE>
__global__ __launch_bounds__(256) void k_gemm(const float* __restrict__ X, const float* __restrict__ W,
                                              const float* __restrict__ dinv, const float* __restrict__ bias,
                                              float* __restrict__ G, int N) {
  __shared__ float Wl[64 * 128];   // half of W (K-split), 32 KB
  __shared__ float Xl[32 * 128];   // X tile, 16 KB
  int tid = threadIdx.x;
  int row0 = blockIdx.x * 32;

  // load X tile (with fused transform for MODE 1)
  for (int i = tid; i < 1024; i += 256) {
    int r = i >> 5;
    int cc = i & 31;
    int grow = row0 + r;
    int gr = (grow < N) ? grow : (N - 1);
    float4 v = ((const float4*)X)[(size_t)gr * 32 + cc];
    if (MODE == 1) {
      float di = dinv[gr];
      v.x = fmaxf(fmaf(di, v.x, bias[cc * 4 + 0]), 0.f);
      v.y = fmaxf(fmaf(di, v.y, bias[cc * 4 + 1]), 0.f);
      v.z = fmaxf(fmaf(di, v.z, bias[cc * 4 + 2]), 0.f);
      v.w = fmaxf(fmaf(di, v.w, bias[cc * 4 + 3]), 0.f);
    }
    ((float4*)Xl)[i] = v;
  }

  int cg = tid & 31;   // col group: cols cg*4 .. cg*4+3
  int rg = tid >> 5;   // row group: rows rg*4 .. rg*4+3
  float acc[4][4];
  for (int a = 0; a < 4; a++)
    for (int b = 0; b < 4; b++) acc[a][b] = 0.f;

  for (int kt = 0; kt < 2; kt++) {
    __syncthreads();  // Xl ready (kt=0) / previous Wl reads done (kt=1)
    for (int i = tid; i < 2048; i += 256)
      ((float4*)Wl)[i] = ((const float4*)W)[kt * 2048 + i];
    __syncthreads();
#pragma unroll 8
    for (int k = 0; k < 64; k++) {
      float4 w = ((const float4*)(Wl + k * 128))[cg];
      float x0 = Xl[(rg * 4 + 0) * 128 + kt * 64 + k];
      float x1 = Xl[(rg * 4 + 1) * 128 + kt * 64 + k];
      float x2 = Xl[(rg * 4 + 2) * 128 + kt * 64 + k];
      float x3 = Xl[(rg * 4 + 3) * 128 + kt * 64 + k];
      acc[0][0] = fmaf(x0, w.x, acc[0][0]);
      acc[0][1] = fmaf(x0, w.y, acc[0][1]);
      acc[0][2] = fmaf(x0, w.z, acc[0][2]);
      acc[0][3] = fmaf(x0, w.w, acc[0][3]);
      acc[1][0] = fmaf(x1, w.x, acc[1][0]);
      acc[1][1] = fmaf(x1, w.y, acc[1][1]);
      acc[1][2] = fmaf(x1, w.z, acc[1][2]);
      acc[1][3] = fmaf(x1, w.w, acc[1][3]);
      acc[2][0] = fmaf(x2, w.x, acc[2][0]);
      acc[2][1] = fmaf(x2, w.y, acc[2][1]);
      acc[2][2] = fmaf(x2, w.z, acc[2][2]);
      acc[2][3] = fmaf(x2, w.w, acc[2][3]);
      acc[3][0] = fmaf(x3, w.x, acc[3][0]);
      acc[3][1] = fmaf(x3, w.y, acc[3][1]);
      acc[3][2] = fmaf(x3, w.z, acc[3][2]);
      acc[3][3] = fmaf(x3, w.w, acc[3][3]);
    }
  }

  for (int ri = 0; ri < 4; ri++) {
    int grow = row0 + rg * 4 + ri;
    if (grow < N) {
      float di = dinv[grow];
      float4 o;
      o.x = di * acc[ri][0];
      o.y = di * acc[ri][1];
      o.z = di * acc[ri][2];
      o.w = di * acc[ri][3];
      ((float4*)(G + (size_t)grow * 128))[cg] = o;
    }
  }
}

// agg[v][f] = g[v][f] + sum over in-edges g[src][f].  One block (128 thr) per node.
__global__ __launch_bounds__(128) void k_agg(const float* __restrict__ g, const int* __restrict__ offs,
                                             const int* __restrict__ csr_src, float* __restrict__ agg, int N) {
  int v = blockIdx.x;
  int tid = threadIdx.x;
  float acc = g[(size_t)v * 128 + tid];
  int s0 = offs[v], s1 = offs[v + 1];
  for (int i = s0; i < s1; i++) {
    int s = csr_src[i];
    acc += g[(size_t)s * 128 + tid];
  }
  agg[(size_t)v * 128 + tid] = acc;
}

// layer 3 GEMV: g3[r] = dinv[r] * sum_k relu(dinv[r]*agg2[r][k] + b2[k]) * W3[k]
__global__ __launch_bounds__(256) void k_gemv3(const float* __restrict__ agg2, const float* __restrict__ W3,
                                               const float* __restrict__ dinv, const float* __restrict__ b2,
                                               float* __restrict__ g3, int N) {
  int wave = threadIdx.x >> 6;
  int lane = threadIdx.x & 63;
  int r = blockIdx.x * 4 + wave;
  if (r >= N) return;
  float di = dinv[r];
  float2 xv = ((const float2*)agg2)[(size_t)r * 64 + lane];
  float2 wv = ((const float2*)W3)[lane];
  float2 bb = ((const float2*)b2)[lane];
  float v0 = fmaxf(fmaf(di, xv.x, bb.x), 0.f);
  float v1 = fmaxf(fmaf(di, xv.y, bb.y), 0.f);
  float s = v0 * wv.x + v1 * wv.y;
  for (int d = 32; d > 0; d >>= 1) s += __shfl_down(s, d, 64);
  if (lane == 0) g3[r] = di * s;
}

__global__ __launch_bounds__(256) void k_agg3(const float* __restrict__ g3, const int* __restrict__ offs,
                                              const int* __restrict__ csr_src, const float* __restrict__ dinv,
                                              const float* __restrict__ b3, float* __restrict__ out, int N) {
  int v = blockIdx.x * 256 + threadIdx.x;
  if (v < N) {
    float acc = g3[v];
    int s0 = offs[v], s1 = offs[v + 1];
    for (int i = s0; i < s1; i++) acc += g3[csr_src[i]];
    out[v] = dinv[v] * acc + b3[0];
  }
}

extern "C" void kernel_launch(void* const* d_in, const int* in_sizes, int n_in,
                              void* d_out, int out_size, void* d_ws, size_t ws_size,
                              hipStream_t stream) {
  const float* x = (const float*)d_in[0];
  const int* ei = (const int*)d_in[1];    // harness stages integers as int32
  const float* W1 = (const float*)d_in[2];
  const float* b1 = (const float*)d_in[3];
  const float* W2 = (const float*)d_in[4];
  const float* b2 = (const float*)d_in[5];
  const float* W3 = (const float*)d_in[6];
  const float* b3 = (const float*)d_in[7];
  float* out = (float*)d_out;

  int N = in_sizes[0] / 128;  // 50000
  int E = in_sizes[1] / 2;    // 800000

  char* base = (char*)d_ws;
  size_t off = 0;
  auto alloc = [&](size_t bytes) -> void* {
    void* p = base + off;
    off += (bytes + 255) & ~(size_t)255;
    return p;
  };
  int* cnt = (int*)alloc((size_t)N * 4);
  int* offs = (int*)alloc(((size_t)N + 1) * 4);
  int* cursor = (int*)alloc((size_t)N * 4);
  int* csr = (int*)alloc((size_t)E * 4);
  float* dinv = (float*)alloc((size_t)N * 4);
  int* bsum = (int*)alloc(4096 * 4);
  float* bufA = (float*)alloc((size_t)N * 128 * 4);
  float* bufB = (float*)alloc((size_t)N * 128 * 4);
  float* g3 = (float*)alloc((size_t)N * 4);
  (void)ws_size;

  hipMemsetAsync(cnt, 0, (size_t)N * 4, stream);

  int gE = (E + 255) / 256;
  int gN = (N + 255) / 256;
  k_prep<<<gE, 256, 0, stream>>>(ei, cnt, E, N);
  k_dinv<<<gN, 256, 0, stream>>>(cnt, dinv, N);
  k_scan1<<<gN, 256, 0, stream>>>(cnt, offs, bsum, N);
  k_scan2<<<1, 256, 0, stream>>>(bsum, gN);
  k_scan3<<<gN, 256, 0, stream>>>(offs, bsum, cursor, N, E);
  k_fill<<<gE, 256, 0, stream>>>(ei, cursor, csr, E, N);

  int gG = (N + 31) / 32;
  k_gemm<0><<<gG, 256, 0, stream>>>(x, W1, dinv, nullptr, bufA, N);
  k_agg<<<N, 128, 0, stream>>>(bufA, offs, csr, bufB, N);
  k_gemm<1><<<gG, 256, 0, stream>>>(bufB, W2, dinv, b1, bufA, N);
  k_agg<<<N, 128, 0, stream>>>(bufA, offs, csr, bufB, N);
  int gV = (N + 3) / 4;
  k_gemv3<<<gV, 256, 0, stream>>>(bufB, W3, dinv, b2, g3, N);
  k_agg3<<<gN, 256, 0, stream>>>(g3, offs, csr, dinv, b3, out, N);
}

// Round 5
// 368.074 us; speedup vs baseline: 1.1675x; 1.1675x over previous
//
#include <hip/hip_runtime.h>

// GCN 3-layer fused pipeline for MI355X.
// N=50000 nodes, E=800000 edges, F=128 features.
// edge_index staged as int32, layout [row[0..E), col[0..E)].
// Per layer: g = dinv * (X' @ W)  (X' = relu(dinv*agg_prev + b_prev) fused into load)
//            agg[v] = g[v] + sum_{in-edges} g[src]  (CSR gather, no atomics)
// R2: k_agg rewritten wave-per-node, float4 row gathers, 4-deep MLP pipeline
//     (was latency-bound at 2.57 TB/s, VALUBusy 7%).
// R3/R4: identical resubmits (benches lost to GPU acquisition timeouts).

__global__ __launch_bounds__(256) void k_prep(const int* __restrict__ ei,
                                              int* __restrict__ cnt, int E, int N) {
  int e = blockIdx.x * 256 + threadIdx.x;
  if (e < E) {
    unsigned c = (unsigned)ei[E + e];
    if (c < (unsigned)N) atomicAdd(&cnt[c], 1);
  }
}

// block-local exclusive scan of cnt; also emits dinv (fused, saves a launch)
__global__ __launch_bounds__(256) void k_scan1(const int* __restrict__ cnt, int* __restrict__ offs,
                                               int* __restrict__ bsum, float* __restrict__ dinv, int N) {
  __shared__ int s[256];
  int tid = threadIdx.x;
  int i = blockIdx.x * 256 + tid;
  int v = (i < N) ? cnt[i] : 0;
  if (i < N) dinv[i] = rsqrtf((float)(v + 1));  // +1 self loop; always > 0
  s[tid] = v;
  __syncthreads();
  for (int d = 1; d < 256; d <<= 1) {
    int t = (tid >= d) ? s[tid - d] : 0;
    __syncthreads();
    s[tid] += t;
    __syncthreads();
  }
  if (i < N) offs[i] = s[tid] - v;
  if (tid == 255) bsum[blockIdx.x] = s[255];
}

__global__ __launch_bounds__(256) void k_scan2(int* __restrict__ bsum, int B) {
  __shared__ int s[256];
  int tid = threadIdx.x;
  int v = (tid < B) ? bsum[tid] : 0;
  s[tid] = v;
  __syncthreads();
  for (int d = 1; d < 256; d <<= 1) {
    int t = (tid >= d) ? s[tid - d] : 0;
    __syncthreads();
    s[tid] += t;
    __syncthreads();
  }
  if (tid < B) bsum[tid] = s[tid] - v;
}

__global__ __launch_bounds__(256) void k_scan3(int* __restrict__ offs, const int* __restrict__ bsum,
                                               int* __restrict__ cursor, int N, int E) {
  int i = blockIdx.x * 256 + threadIdx.x;
  if (i < N) {
    int o = offs[i] + bsum[blockIdx.x];
    offs[i] = o;
    cursor[i] = o;
  }
  if (i == 0) offs[N] = E;
}

__global__ __launch_bounds__(256) void k_fill(const int* __restrict__ ei,
                                              int* __restrict__ cursor, int* __restrict__ csr_src,
                                              int E, int N) {
  int e = blockIdx.x * 256 + threadIdx.x;
  if (e < E) {
    unsigned r = (unsigned)ei[e];
    unsigned c = (unsigned)ei[E + e];
    if (c < (unsigned)N && r < (unsigned)N) {
      int p = atomicAdd(&cursor[c], 1);
      csr_src[p] = (int)r;
    }
  }
}

// GEMM: G[row][col] = dinv[row] * sum_k X'[row][k] * W[k][col]
// MODE 0: X' = X.  MODE 1: X'[r][k] = relu(dinv[r]*X[r][k] + bias[k]).
template <int MODE>
__global__ __launch_bounds__(256) void k_gemm(const float* __restrict__ X, const float* __restrict__ W,
                                              const float* __restrict__ dinv, const float* __restrict__ bias,
                                              float* __restrict__ G, int N) {
  __shared__ float Wl[64 * 128];
  __shared__ float Xl[32 * 128];
  int tid = threadIdx.x;
  int row0 = blockIdx.x * 32;

  for (int i = tid; i < 1024; i += 256) {
    int r = i >> 5;
    int cc = i & 31;
    int grow = row0 + r;
    int gr = (grow < N) ? grow : (N - 1);
    float4 v = ((const float4*)X)[(size_t)gr * 32 + cc];
    if (MODE == 1) {
      float di = dinv[gr];
      v.x = fmaxf(fmaf(di, v.x, bias[cc * 4 + 0]), 0.f);
      v.y = fmaxf(fmaf(di, v.y, bias[cc * 4 + 1]), 0.f);
      v.z = fmaxf(fmaf(di, v.z, bias[cc * 4 + 2]), 0.f);
      v.w = fmaxf(fmaf(di, v.w, bias[cc * 4 + 3]), 0.f);
    }
    ((float4*)Xl)[i] = v;
  }

  int cg = tid & 31;
  int rg = tid >> 5;
  float acc[4][4];
  for (int a = 0; a < 4; a++)
    for (int b = 0; b < 4; b++) acc[a][b] = 0.f;

  for (int kt = 0; kt < 2; kt++) {
    __syncthreads();
    for (int i = tid; i < 2048; i += 256)
      ((float4*)Wl)[i] = ((const float4*)W)[kt * 2048 + i];
    __syncthreads();
#pragma unroll 8
    for (int k = 0; k < 64; k++) {
      float4 w = ((const float4*)(Wl + k * 128))[cg];
      float x0 = Xl[(rg * 4 + 0) * 128 + kt * 64 + k];
      float x1 = Xl[(rg * 4 + 1) * 128 + kt * 64 + k];
      float x2 = Xl[(rg * 4 + 2) * 128 + kt * 64 + k];
      float x3 = Xl[(rg * 4 + 3) * 128 + kt * 64 + k];
      acc[0][0] = fmaf(x0, w.x, acc[0][0]);
      acc[0][1] = fmaf(x0, w.y, acc[0][1]);
      acc[0][2] = fmaf(x0, w.z, acc[0][2]);
      acc[0][3] = fmaf(x0, w.w, acc[0][3]);
      acc[1][0] = fmaf(x1, w.x, acc[1][0]);
      acc[1][1] = fmaf(x1, w.y, acc[1][1]);
      acc[1][2] = fmaf(x1, w.z, acc[1][2]);
      acc[1][3] = fmaf(x1, w.w, acc[1][3]);
      acc[2][0] = fmaf(x2, w.x, acc[2][0]);
      acc[2][1] = fmaf(x2, w.y, acc[2][1]);
      acc[2][2] = fmaf(x2, w.z, acc[2][2]);
      acc[2][3] = fmaf(x2, w.w, acc[2][3]);
      acc[3][0] = fmaf(x3, w.x, acc[3][0]);
      acc[3][1] = fmaf(x3, w.y, acc[3][1]);
      acc[3][2] = fmaf(x3, w.z, acc[3][2]);
      acc[3][3] = fmaf(x3, w.w, acc[3][3]);
    }
  }

  for (int ri = 0; ri < 4; ri++) {
    int grow = row0 + rg * 4 + ri;
    if (grow < N) {
      float di = dinv[grow];
      float4 o;
      o.x = di * acc[ri][0];
      o.y = di * acc[ri][1];
      o.z = di * acc[ri][2];
      o.w = di * acc[ri][3];
      ((float4*)(G + (size_t)grow * 128))[cg] = o;
    }
  }
}

// agg[v][f] = g[v][f] + sum over in-edges g[src][f].
// One wave per node; half-wave (32 lanes x float4) = one 512B row per load.
// Halves own alternate edges; 4-deep manual pipeline -> 8 rows in flight/wave.
__global__ __launch_bounds__(256) void k_agg(const float* __restrict__ g, const int* __restrict__ offs,
                                             const int* __restrict__ csr_src, float* __restrict__ agg, int N) {
  int v = blockIdx.x * 4 + (threadIdx.x >> 6);
  if (v >= N) return;
  int lane = threadIdx.x & 63;
  int half = lane >> 5;      // 0 or 1
  int fc = lane & 31;        // float4 index within row
  const float4* __restrict__ G4 = (const float4*)g;

  float4 a0 = make_float4(0.f, 0.f, 0.f, 0.f);
  float4 a1 = make_float4(0.f, 0.f, 0.f, 0.f);
  if (half == 0) a0 = G4[(size_t)v * 32 + fc];  // self row (overlaps with csr loads)

  int s0 = offs[v], s1 = offs[v + 1];
  int i = s0 + half;
  // main: 4 edges per half per iter, independent gathers
  for (; i + 6 < s1; i += 8) {
    int e0 = csr_src[i];
    int e1 = csr_src[i + 2];
    int e2 = csr_src[i + 4];
    int e3 = csr_src[i + 6];
    float4 r0 = G4[(size_t)e0 * 32 + fc];
    float4 r1 = G4[(size_t)e1 * 32 + fc];
    float4 r2 = G4[(size_t)e2 * 32 + fc];
    float4 r3 = G4[(size_t)e3 * 32 + fc];
    a0.x += r0.x; a0.y += r0.y; a0.z += r0.z; a0.w += r0.w;
    a1.x += r1.x; a1.y += r1.y; a1.z += r1.z; a1.w += r1.w;
    a0.x += r2.x; a0.y += r2.y; a0.z += r2.z; a0.w += r2.w;
    a1.x += r3.x; a1.y += r3.y; a1.z += r3.z; a1.w += r3.w;
  }
  for (; i < s1; i += 2) {
    int e = csr_src[i];
    float4 r = G4[(size_t)e * 32 + fc];
    a0.x += r.x; a0.y += r.y; a0.z += r.z; a0.w += r.w;
  }
  a0.x += a1.x; a0.y += a1.y; a0.z += a1.z; a0.w += a1.w;

  // combine the two halves (lane ^ 32)
  a0.x += __shfl_xor(a0.x, 32, 64);
  a0.y += __shfl_xor(a0.y, 32, 64);
  a0.z += __shfl_xor(a0.z, 32, 64);
  a0.w += __shfl_xor(a0.w, 32, 64);

  if (half == 0) ((float4*)agg)[(size_t)v * 32 + fc] = a0;
}

// layer 3 GEMV: g3[r] = dinv[r] * sum_k relu(dinv[r]*agg2[r][k] + b2[k]) * W3[k]
__global__ __launch_bounds__(256) void k_gemv3(const float* __restrict__ agg2, const float* __restrict__ W3,
                                               const float* __restrict__ dinv, const float* __restrict__ b2,
                                               float* __restrict__ g3, int N) {
  int wave = threadIdx.x >> 6;
  int lane = threadIdx.x & 63;
  int r = blockIdx.x * 4 + wave;
  if (r >= N) return;
  float di = dinv[r];
  float2 xv = ((const float2*)agg2)[(size_t)r * 64 + lane];
  float2 wv = ((const float2*)W3)[lane];
  float2 bb = ((const float2*)b2)[lane];
  float v0 = fmaxf(fmaf(di, xv.x, bb.x), 0.f);
  float v1 = fmaxf(fmaf(di, xv.y, bb.y), 0.f);
  float s = v0 * wv.x + v1 * wv.y;
  for (int d = 32; d > 0; d >>= 1) s += __shfl_down(s, d, 64);
  if (lane == 0) g3[r] = di * s;
}

__global__ __launch_bounds__(256) void k_agg3(const float* __restrict__ g3, const int* __restrict__ offs,
                                              const int* __restrict__ csr_src, const float* __restrict__ dinv,
                                              const float* __restrict__ b3, float* __restrict__ out, int N) {
  int v = blockIdx.x * 256 + threadIdx.x;
  if (v < N) {
    float acc = g3[v];
    int i = offs[v], s1 = offs[v + 1];
    for (; i + 3 < s1; i += 4) {
      int e0 = csr_src[i], e1 = csr_src[i + 1], e2 = csr_src[i + 2], e3 = csr_src[i + 3];
      float r0 = g3[e0], r1 = g3[e1], r2 = g3[e2], r3 = g3[e3];
      acc += r0 + r1 + r2 + r3;
    }
    for (; i < s1; i++) acc += g3[csr_src[i]];
    out[v] = dinv[v] * acc + b3[0];
  }
}

extern "C" void kernel_launch(void* const* d_in, const int* in_sizes, int n_in,
                              void* d_out, int out_size, void* d_ws, size_t ws_size,
                              hipStream_t stream) {
  const float* x = (const float*)d_in[0];
  const int* ei = (const int*)d_in[1];
  const float* W1 = (const float*)d_in[2];
  const float* b1 = (const float*)d_in[3];
  const float* W2 = (const float*)d_in[4];
  const float* b2 = (const float*)d_in[5];
  const float* W3 = (const float*)d_in[6];
  const float* b3 = (const float*)d_in[7];
  float* out = (float*)d_out;

  int N = in_sizes[0] / 128;  // 50000
  int E = in_sizes[1] / 2;    // 800000

  char* base = (char*)d_ws;
  size_t off = 0;
  auto alloc = [&](size_t bytes) -> void* {
    void* p = base + off;
    off += (bytes + 255) & ~(size_t)255;
    return p;
  };
  int* cnt = (int*)alloc((size_t)N * 4);
  int* offs = (int*)alloc(((size_t)N + 1) * 4);
  int* cursor = (int*)alloc((size_t)N * 4);
  int* csr = (int*)alloc((size_t)E * 4);
  float* dinv = (float*)alloc((size_t)N * 4);
  int* bsum = (int*)alloc(4096 * 4);
  float* bufA = (float*)alloc((size_t)N * 128 * 4);
  float* bufB = (float*)alloc((size_t)N * 128 * 4);
  float* g3 = (float*)alloc((size_t)N * 4);
  (void)ws_size;

  hipMemsetAsync(cnt, 0, (size_t)N * 4, stream);

  int gE = (E + 255) / 256;
  int gN = (N + 255) / 256;
  k_prep<<<gE, 256, 0, stream>>>(ei, cnt, E, N);
  k_scan1<<<gN, 256, 0, stream>>>(cnt, offs, bsum, dinv, N);
  k_scan2<<<1, 256, 0, stream>>>(bsum, gN);
  k_scan3<<<gN, 256, 0, stream>>>(offs, bsum, cursor, N, E);
  k_fill<<<gE, 256, 0, stream>>>(ei, cursor, csr, E, N);

  int gG = (N + 31) / 32;
  int gA = (N + 3) / 4;
  k_gemm<0><<<gG, 256, 0, stream>>>(x, W1, dinv, nullptr, bufA, N);
  k_agg<<<gA, 256, 0, stream>>>(bufA, offs, csr, bufB, N);
  k_gemm<1><<<gG, 256, 0, stream>>>(bufB, W2, dinv, b1, bufA, N);
  k_agg<<<gA, 256, 0, stream>>>(bufA, offs, csr, bufB, N);
  int gV = (N + 3) / 4;
  k_gemv3<<<gV, 256, 0, stream>>>(bufB, W3, dinv, b2, g3, N);
  k_agg3<<<gN, 256, 0, stream>>>(g3, offs, csr, dinv, b3, out, N);
}